// Round 1
// baseline (28.572 us; speedup 1.0000x reference)
//
#include <hip/hip_runtime.h>

// GCNConv on full upper-triangular graph + self loops, B=512, N=64, C=O=256.
// out[b,i,:] = relu( (1/sqrt(i+1)) * sum_{j<=i} (X[b]W)[j,:]/sqrt(j+1) + bias )
//
// Plan: wprep converts W (f32, [K][N]) -> Wt (bf16, [N][K]) in d_ws.
//       gcn_fused: 1 block per batch graph, 256 thr (4 waves), each wave owns
//       a 64-col panel. X[b] staged to LDS as bf16 (XOR-swizzled rows), GEMM
//       via mfma_f32_16x16x32_bf16, prefix-scan along nodes in registers (f32),
//       fused bias+relu+store.

#define BATCH 512
#define NNODE 64
#define CIN   256
#define COUT  256

typedef __bf16 bf16x8 __attribute__((ext_vector_type(8)));
typedef float  f32x4  __attribute__((ext_vector_type(4)));

__device__ __forceinline__ unsigned int f2bf_bits(float f) {
    // round-to-nearest-even f32 -> bf16 (inputs are finite, no NaN handling)
    unsigned int u = __builtin_bit_cast(unsigned int, f);
    return (u + 0x7fffu + ((u >> 16) & 1u)) >> 16;
}

__global__ __launch_bounds__(256, 2) void gcn_fused(
    const float* __restrict__ X,
    const unsigned short* __restrict__ WT,   // bf16 bits, layout [COUT][CIN]
    const float* __restrict__ bias,
    float* __restrict__ out)
{
    __shared__ uint4 Xs4[2048];              // 32 KiB: X[b] as bf16, swizzled
    unsigned char* Xs = (unsigned char*)Xs4;

    const int tid  = threadIdx.x;
    const int bidx = blockIdx.x;
    const float* xb = X + (size_t)bidx * (NNODE * CIN);

    // ---- stage X[b] (64x256 f32) -> LDS bf16, byte ^= (row&7)<<4 swizzle ----
#pragma unroll
    for (int i = 0; i < 8; ++i) {
        int ch  = tid + i * 256;             // 8-float chunk id (2048 chunks)
        int row = ch >> 5;                   // 32 chunks per row
        int c8  = (ch & 31) << 3;
        const float4* p = reinterpret_cast<const float4*>(xb + row * CIN + c8);
        float4 v0 = p[0];
        float4 v1 = p[1];
        unsigned int w0 = f2bf_bits(v0.x) | (f2bf_bits(v0.y) << 16);
        unsigned int w1 = f2bf_bits(v0.z) | (f2bf_bits(v0.w) << 16);
        unsigned int w2 = f2bf_bits(v1.x) | (f2bf_bits(v1.y) << 16);
        unsigned int w3 = f2bf_bits(v1.z) | (f2bf_bits(v1.w) << 16);
        int byte = (row << 9) + (c8 << 1);
        byte ^= (row & 7) << 4;
        *reinterpret_cast<uint4*>(Xs + byte) = make_uint4(w0, w1, w2, w3);
    }
    __syncthreads();

    const int lane = tid & 63;
    const int w    = tid >> 6;     // wave id: owns output cols [w*64, w*64+64)
    const int g    = lane >> 4;    // 16-lane group (k-group for A/B, row-group for C)
    const int c    = lane & 15;

    f32x4 acc[4][4] = {};          // [mt][nt]; C/D: row = mt*16+g*4+r, col = nt*16+c
    const int swz = (c & 7) << 4;
    const unsigned short* WTb = WT + (size_t)(w * 64 + c) * CIN + g * 8;

#pragma unroll
    for (int kk = 0; kk < 8; ++kk) {         // K = 256 = 8 x 32
        bf16x8 a[4], bfr[4];
#pragma unroll
        for (int mt = 0; mt < 4; ++mt) {
            // A[row = mt*16+c][k = kk*32 + g*8 .. +7], swizzled
            int byte = ((mt * 16 + c) << 9) + (kk << 6) + (g << 4);
            byte ^= swz;
            a[mt] = *reinterpret_cast<const bf16x8*>(Xs + byte);
        }
#pragma unroll
        for (int nt = 0; nt < 4; ++nt)
            // B[k = kk*32+g*8..+7][col = nt*16+c]  ==  Wt[col][k..k+7] contiguous
            bfr[nt] = *reinterpret_cast<const bf16x8*>(WTb + nt * 16 * CIN + kk * 32);
#pragma unroll
        for (int mt = 0; mt < 4; ++mt)
#pragma unroll
            for (int nt = 0; nt < 4; ++nt)
                acc[mt][nt] = __builtin_amdgcn_mfma_f32_16x16x32_bf16(
                    a[mt], bfr[nt], acc[mt][nt], 0, 0, 0);
    }

    // ---- epilogue: scale rows by 1/sqrt(j+1), prefix-sum over 64 rows ----
    // per-lane inclusive scan within each 4-row chunk (mt, g)
    float t[4][4];                 // chunk totals [mt][nt]
#pragma unroll
    for (int mt = 0; mt < 4; ++mt) {
        const int rbase = mt * 16 + g * 4;
        float d0 = rsqrtf((float)(rbase + 1));
        float d1 = rsqrtf((float)(rbase + 2));
        float d2 = rsqrtf((float)(rbase + 3));
        float d3 = rsqrtf((float)(rbase + 4));
#pragma unroll
        for (int nt = 0; nt < 4; ++nt) {
            f32x4 v = acc[mt][nt];
            v[0] *= d0; v[1] *= d1; v[2] *= d2; v[3] *= d3;
            v[1] += v[0]; v[2] += v[1]; v[3] += v[2];
            acc[mt][nt] = v;
            t[mt][nt] = v[3];
        }
    }

    // cross-chunk exclusive scan: 16 chunks (q = mt*4+g) per column, via shfl
    float O[4][4];                 // [nt][mt] exclusive offsets for this lane's g
#pragma unroll
    for (int nt = 0; nt < 4; ++nt) {
        float S = 0.0f;
#pragma unroll
        for (int q = 0; q < 16; ++q) {
            const int mtq = q >> 2, gq = q & 3;
            float v = __shfl(t[mtq][nt], c + (gq << 4), 64);
            if (gq == g) O[nt][mtq] = S;
            S += v;
        }
    }

    float bias_c[4];
#pragma unroll
    for (int nt = 0; nt < 4; ++nt)
        bias_c[nt] = bias[w * 64 + nt * 16 + c];

    // out[row] = (P_incl[row]) * 1/sqrt(row+1) + bias, relu
    float* ob = out + (size_t)bidx * (NNODE * COUT) + (w * 64 + c);
#pragma unroll
    for (int mt = 0; mt < 4; ++mt) {
#pragma unroll
        for (int r = 0; r < 4; ++r) {
            const int row = mt * 16 + g * 4 + r;
            float dr = rsqrtf((float)(row + 1));
#pragma unroll
            for (int nt = 0; nt < 4; ++nt) {
                float val = (acc[mt][nt][r] + O[nt][mt]) * dr + bias_c[nt];
                ob[row * COUT + nt * 16] = fmaxf(val, 0.0f);
            }
        }
    }
}

// W (f32, [K=256][N=256]) -> Wt (bf16 bits, [N=256][K=256]) via LDS tile transpose
__global__ void wprep(const float* __restrict__ W, unsigned short* __restrict__ Wt) {
    __shared__ unsigned short tile[64][72];
    const int tid = threadIdx.x;
    const int tk  = blockIdx.x & 3;          // k tile
    const int tn  = blockIdx.x >> 2;         // n tile
#pragma unroll
    for (int i = 0; i < 16; ++i) {
        int idx = tid + i * 256;
        int r  = idx >> 6;                   // k within tile
        int cc = idx & 63;                   // n within tile
        tile[cc][r] = (unsigned short)f2bf_bits(W[(tk * 64 + r) * 256 + tn * 64 + cc]);
    }
    __syncthreads();
#pragma unroll
    for (int i = 0; i < 16; ++i) {
        int idx = tid + i * 256;
        int rr = idx >> 6;                   // n within tile
        int cc = idx & 63;                   // k within tile
        Wt[(tn * 64 + rr) * 256 + tk * 64 + cc] = tile[rr][cc];
    }
}

extern "C" void kernel_launch(void* const* d_in, const int* in_sizes, int n_in,
                              void* d_out, int out_size, void* d_ws, size_t ws_size,
                              hipStream_t stream) {
    const float* x = (const float*)d_in[0];
    const float* W = (const float*)d_in[1];
    const float* b = (const float*)d_in[2];
    float* out = (float*)d_out;
    unsigned short* Wt = (unsigned short*)d_ws;  // 128 KiB scratch

    hipLaunchKernelGGL(wprep, dim3(16), dim3(256), 0, stream, W, Wt);
    hipLaunchKernelGGL(gcn_fused, dim3(BATCH), dim3(256), 0, stream, x, Wt, b, out);
}